// Round 11
// baseline (2277.221 us; speedup 1.0000x reference)
//
#include <hip/hip_runtime.h>

#define N 8192
#define IN_F 512
#define OUT_F 128
#define SPLITK 8
#define KC 1024
#define NW (N / 8)
#define LOG2E 1.4426950408889634f
#define LN2 0.6931471805599453f

typedef __attribute__((ext_vector_type(4))) float f32x4;
typedef __attribute__((ext_vector_type(8))) short bf16x8;
typedef __attribute__((ext_vector_type(8))) unsigned short u16x8;
typedef __attribute__((ext_vector_type(4))) int i32x4;

__device__ __forceinline__ short f2bf(float f) {
    union { float f; unsigned u; } c; c.f = f;
    unsigned r = c.u + 0x7FFFu + ((c.u >> 16) & 1u);
    return (short)(r >> 16);
}

__device__ __forceinline__ float exp2fast(float x) {
#if __has_builtin(__builtin_amdgcn_exp2f)
    return __builtin_amdgcn_exp2f(x);
#else
    return __expf(x * LN2);
#endif
}

__device__ __forceinline__ void load_lds16(const void* g, void* l) {
    __builtin_amdgcn_global_load_lds((const __attribute__((address_space(1))) unsigned*)g,
                                     (__attribute__((address_space(3))) unsigned*)l,
                                     16, 0, 0);
}

// ---------------------------------------------------------------- prep: W f32 -> WT bf16 [OUT_F][IN_F]; zero group counters
__global__ __launch_bounds__(256) void prep(const float* __restrict__ W,
                                            short* __restrict__ WT,
                                            int* __restrict__ cnt) {
    if (blockIdx.x == 0 && threadIdx.x < 512) cnt[threadIdx.x] = 0;
    int idx = blockIdx.x * 256 + threadIdx.x;   // 65536 total
    int n = idx & (OUT_F - 1);
    int k = idx >> 7;
    WT[(size_t)n * IN_F + k] = f2bf(W[idx]);
}

// ---------------------------------------------------------------- gemm_hW: Wh=h@W -> Bpack (MFMA-fragment-packed) + fused s,t
__global__ __launch_bounds__(256) void gemm_hW(const float* __restrict__ h,
                                               const short* __restrict__ WT,
                                               const float* __restrict__ a,
                                               short* __restrict__ Bpack,
                                               float* __restrict__ sOut,
                                               float* __restrict__ tOut) {
    const int tid = threadIdx.x;
    const int wave = tid >> 6, lane = tid & 63;
    const int row16 = lane & 15, kgrp = lane >> 4;
    const int m0 = blockIdx.x * 16;
    const int kbase = wave * 128;

    f32x4 acc[8] = {};
    const float4* hp = (const float4*)(h + (size_t)(m0 + row16) * IN_F + kbase);

#pragma unroll
    for (int kk = 0; kk < 128; kk += 32) {
        float4 u0 = hp[kk / 4 + kgrp * 2];
        float4 u1 = hp[kk / 4 + kgrp * 2 + 1];
        bf16x8 af;
        af[0] = f2bf(u0.x); af[1] = f2bf(u0.y); af[2] = f2bf(u0.z); af[3] = f2bf(u0.w);
        af[4] = f2bf(u1.x); af[5] = f2bf(u1.y); af[6] = f2bf(u1.z); af[7] = f2bf(u1.w);
#pragma unroll
        for (int nt = 0; nt < 8; nt++) {
            bf16x8 bf_ = *(const bf16x8*)(WT + (size_t)(nt * 16 + row16) * IN_F + kbase + kk + kgrp * 8);
            acc[nt] = __builtin_amdgcn_mfma_f32_16x16x32_bf16(af, bf_, acc[nt], 0, 0, 0);
        }
    }

    __shared__ float red[4][16][132];
#pragma unroll
    for (int nt = 0; nt < 8; nt++)
#pragma unroll
        for (int r = 0; r < 4; r++)
            red[wave][kgrp * 4 + r][nt * 16 + row16] = acc[nt][r];
    __syncthreads();

    const int row = tid >> 4, seg = tid & 15;
    float v[8];
#pragma unroll
    for (int e = 0; e < 8; e++) {
        int c = seg * 8 + e;
        v[e] = red[0][row][c] + red[1][row][c] + red[2][row][c] + red[3][row][c];
    }
    float sp = 0.f, tp = 0.f;
#pragma unroll
    for (int e = 0; e < 8; e++) {
        sp += v[e] * a[seg * 8 + e];
        tp += v[e] * a[OUT_F + seg * 8 + e];
    }
    sp += __shfl_xor(sp, 1); tp += __shfl_xor(tp, 1);
    sp += __shfl_xor(sp, 2); tp += __shfl_xor(tp, 2);
    sp += __shfl_xor(sp, 4); tp += __shfl_xor(tp, 4);
    sp += __shfl_xor(sp, 8); tp += __shfl_xor(tp, 8);
    if (seg == 0) {
        sOut[m0 + row] = sp * LOG2E;
        tOut[m0 + row] = tp * LOG2E;
    }

    // Bpack scatter: v[e] is Wh[k=m0+row][n=seg*8+e]
    {
        const int k = m0 + row;
        const int G = k >> 5;
        const int ksub = (k >> 3) & 3;
        const int elem = k & 7;
        short* bp = Bpack + ((size_t)(G * 8 + (seg >> 1)) * 64 + ksub * 16 + (seg & 1) * 8) * 8 + elem;
#pragma unroll
        for (int e = 0; e < 8; e++)
            bp[e * 8] = f2bf(v[e]);
    }
}

// ---------------------------------------------------------------- maskattn: 128 units of [32 mask-producer blocks | 8 attn blocks].
// Producers: 2 adj rows each, row-linear NT stream -> bitmask + release-add on 16-row-group counter.
// Attn: polls its 4 group counters (bounded; fallback = self-compute from adj -> never deadlocks),
// builds swizzled LDS mask tile, then r10's proven body (Bpack LDS stage, t direct from global).
// kb = (b%40)-32 keeps XCD pinning (40 % 8 == 0). LDS exactly 40960 B -> 4 blocks/CU.
__global__ __launch_bounds__(256, 4) void maskattn(const int* __restrict__ adj,
                                                   const short* __restrict__ Bpack,
                                                   const float* __restrict__ s,
                                                   const float* __restrict__ t,
                                                   unsigned short* __restrict__ num,
                                                   float* __restrict__ lpart,
                                                   unsigned char* __restrict__ maskR,
                                                   int* __restrict__ cnt) {
    const int b = blockIdx.x;
    const int mbg = b / 40, rr = b % 40;
    const int tid = threadIdx.x;
    const int wave = tid >> 6, lane = tid & 63;

    __shared__ __align__(16) short Bs[2][8192];        // 32768 B: [parity][d*4096 + ni*512 + lane*8]
    __shared__ __align__(16) unsigned char mk[8192];   // 8192 B: swizzled 64x128B mask tile

    if (rr < 32) {
        // ------------------------------ mask producer: rows mbg*64 + rr*2 + (wave>>1) ------------------------------
        const int row = mbg * 64 + rr * 2 + (wave >> 1);
        const int half = wave & 1;
        const i32x4* ap = (const i32x4*)(adj + (size_t)row * N);
        unsigned char* mp = maskR + (size_t)row * NW;
#pragma unroll
        for (int it = 0; it < 8; it++) {
            int c4 = (half * 8 + it) * 128 + lane * 2;
            i32x4 a0 = __builtin_nontemporal_load(ap + c4);
            i32x4 a1 = __builtin_nontemporal_load(ap + c4 + 1);
            unsigned bb = (unsigned)(a0.x > 0) | ((unsigned)(a0.y > 0) << 1) |
                          ((unsigned)(a0.z > 0) << 2) | ((unsigned)(a0.w > 0) << 3) |
                          ((unsigned)(a1.x > 0) << 4) | ((unsigned)(a1.y > 0) << 5) |
                          ((unsigned)(a1.z > 0) << 6) | ((unsigned)(a1.w > 0) << 7);
            mp[(half * 8 + it) * 64 + lane] = (unsigned char)bb;
        }
        __threadfence();          // flush this thread's mask writes (agent scope)
        __syncthreads();          // all threads' writes fenced before publish
        if (tid == 0)
            __hip_atomic_fetch_add(&cnt[mbg * 4 + (rr >> 3)], 1,
                                   __ATOMIC_RELEASE, __HIP_MEMORY_SCOPE_AGENT);
        return;
    }

    // ------------------------------ attn role ------------------------------
    const int kb = rr - 32;
    const int mb = mbg;
    const int row16 = lane & 15, kgrp = lane >> 4;
    const int m0 = mb * 64 + wave * 16;
    const int m  = m0 + row16;
    const int ks = kb * KC;
    const int rowL = wave * 16 + row16;

    // poll group counters (tid 0 only; result broadcast via LDS scratch in Bs before staging)
    {
        volatile unsigned* rdyS = (volatile unsigned*)&Bs[0][0];
        if (tid == 0) {
            const int g0 = mb * 4;
            unsigned rdy = 0;
            for (int it2 = 0; it2 < 64 && rdy != 15u; ++it2) {
#pragma unroll
                for (int g = 0; g < 4; g++)
                    if (!(rdy & (1u << g))) {
                        int c = __hip_atomic_load(&cnt[g0 + g], __ATOMIC_ACQUIRE, __HIP_MEMORY_SCOPE_AGENT);
                        if (c >= 8) rdy |= 1u << g;
                    }
                if (rdy != 15u) __builtin_amdgcn_s_sleep(32);
            }
            *rdyS = rdy;
        }
        __syncthreads();
        const unsigned rdy = *rdyS;
        __syncthreads();          // everyone has read rdy before Bs[0] is overwritten

        // stage B super 0 (async) while the mask tile is built
        {
            const short* src = Bpack + (size_t)(kb * 32) * 4096;
#pragma unroll
            for (int it = 0; it < 4; it++)
                load_lds16(src + it * 2048 + wave * 512 + lane * 8, &Bs[0][it * 2048 + wave * 512]);
        }

        if (rdy == 15u) {
            // fast path: copy all 64 rows x 128 B from maskR into swizzled mk
            const int row = tid >> 2, q = tid & 3;
            const unsigned char* src = maskR + (size_t)(mb * 64 + row) * NW + (ks >> 3) + q * 32;
            int4 v0 = *(const int4*)(src);
            int4 v1 = *(const int4*)(src + 16);
            const unsigned sw = (unsigned)((row & 7) << 4);
            *(int4*)(mk + row * 128 + ((q * 32) ^ sw)) = v0;
            *(int4*)(mk + row * 128 + ((q * 32 + 16) ^ sw)) = v1;
        } else {
#pragma unroll 1
            for (int g = 0; g < 4; g++) {
                if (rdy & (1u << g)) {
                    if (tid < 64) {
                        const int row = g * 16 + (tid >> 2), q = tid & 3;
                        const unsigned char* src = maskR + (size_t)(mb * 64 + row) * NW + (ks >> 3) + q * 32;
                        int4 v0 = *(const int4*)(src);
                        int4 v1 = *(const int4*)(src + 16);
                        const unsigned sw = (unsigned)((row & 7) << 4);
                        *(int4*)(mk + row * 128 + ((q * 32) ^ sw)) = v0;
                        *(int4*)(mk + row * 128 + ((q * 32 + 16) ^ sw)) = v1;
                    }
                } else {
                    // fallback: compute this group's 16 rows from adj (lane -> 16 consecutive ints)
#pragma unroll 1
                    for (int e = 0; e < 4; e++) {
                        const int row = g * 16 + wave * 4 + e;
                        const int* ab2 = adj + (size_t)(mb * 64 + row) * N + ks + lane * 16;
                        unsigned u = 0;
#pragma unroll
                        for (int j = 0; j < 16; j++) u |= (unsigned)(ab2[j] > 0) << j;
                        const unsigned sw = (unsigned)((row & 7) << 4);
                        *(unsigned short*)(mk + row * 128 + (((unsigned)(lane * 2)) ^ sw)) = (unsigned short)u;
                    }
                }
            }
        }
    }

    auto stageB = [&](int sup, int par) {
        const short* src = Bpack + (size_t)(kb * 32 + sup * 2) * 4096;
#pragma unroll
        for (int it = 0; it < 4; it++)
            load_lds16(src + it * 2048 + wave * 512 + lane * 8, &Bs[par][it * 2048 + wave * 512]);
    };

    const float s_m = s[m];
    f32x4 acc[8] = {};
    float lsum = 0.f;

    __syncthreads();   // mk built + B super 0 staged (drains vmcnt/lgkmcnt)

    for (int sp2 = 0; sp2 < 8; sp2++) {
        const int4 mcur = *(const int4*)(mk + rowL * 128 + (((unsigned)(sp2 * 16)) ^ ((unsigned)((rowL & 7) << 4))));
#pragma unroll
        for (int ss = 0; ss < 2; ss++) {
            const int sp = sp2 * 2 + ss;         // super 0..15
            const int par = ss;                  // == sp & 1
            if (sp + 1 < 16) stageB(sp + 1, par ^ 1);
#pragma unroll
            for (int d = 0; d < 2; d++) {
                const int g = sp * 2 + d;        // slice 0..31
                const unsigned dw = (unsigned)((const int*)&mcur)[ss * 2 + d];
                const unsigned mbyte = (dw >> (kgrp * 8)) & 0xFFu;

                const float* tp = t + ks + g * 32 + kgrp * 8;   // 4 KB slice, L1-resident
                float4 tA = *(const float4*)tp;
                float4 tB = *(const float4*)(tp + 4);
                float tv[8] = { tA.x, tA.y, tA.z, tA.w, tB.x, tB.y, tB.z, tB.w };

                bf16x8 bfr[8];
#pragma unroll
                for (int ni = 0; ni < 8; ni++)
                    bfr[ni] = *(const bf16x8*)(&Bs[par][d * 4096 + ni * 512 + lane * 8]);

                unsigned pu[8];
#pragma unroll
                for (int e = 0; e < 8; e++) {
                    float x = s_m + tv[e];
                    x = fmaxf(x, 0.2f * x);                    // leaky relu
                    float p = exp2fast(x);                     // s,t pre-scaled by log2e
                    unsigned u = __float_as_uint(p) & 0xFFFF0000u;
                    u = ((mbyte >> e) & 1u) ? u : 0u;
                    lsum += __uint_as_float(u);                // consistent with numerator
                    pu[e] = u;
                }
                bf16x8 af;
                unsigned* au = (unsigned*)&af;
#pragma unroll
                for (int q = 0; q < 4; q++) au[q] = (pu[2 * q] >> 16) | pu[2 * q + 1];
#pragma unroll
                for (int ni = 0; ni < 8; ni++)
                    acc[ni] = __builtin_amdgcn_mfma_f32_16x16x32_bf16(af, bfr[ni], acc[ni], 0, 0, 0);
            }
            __syncthreads();   // drains stage of sp+1; guards parity reuse
        }
    }

    // row sum across kgrp lanes
    {
        float v = lsum;
        v += __shfl_xor(v, 16);
        v += __shfl_xor(v, 32);
        if (kgrp == 0) lpart[(size_t)kb * N + m] = v;
    }

    // partial numerator, bf16: C layout row = kgrp*4+r (m within 16), col = ni*16+row16
    unsigned short* np_ = num + ((size_t)kb * N + m0) * OUT_F;
#pragma unroll
    for (int ni = 0; ni < 8; ni++) {
        int n = ni * 16 + row16;
#pragma unroll
        for (int r = 0; r < 4; r++)
            np_[(size_t)(kgrp * 4 + r) * OUT_F + n] = (unsigned short)f2bf(acc[ni][r]);
    }
}

// ---------------------------------------------------------------- finalize: reduce bf16 splits, /l, +rnd, elu
__global__ __launch_bounds__(256) void finalize(const unsigned short* __restrict__ num,
                                                const float* __restrict__ lpart,
                                                const float* __restrict__ rnd,
                                                float* __restrict__ out) {
    int idx = blockIdx.x * 256 + threadIdx.x;   // one thread = 8 outputs
    int m = idx >> 4;
    int c = (idx & 15) * 8;
    size_t g = (size_t)m * OUT_F + c;

    float nm[8] = {};
#pragma unroll
    for (int bk = 0; bk < SPLITK; bk++) {
        u16x8 v = *(const u16x8*)(num + (size_t)bk * N * OUT_F + g);
#pragma unroll
        for (int e = 0; e < 8; e++) nm[e] += __uint_as_float((unsigned)v[e] << 16);
    }
    float l = 0.f;
#pragma unroll
    for (int bk = 0; bk < SPLITK; bk++) l += lpart[(size_t)bk * N + m];
    float inv = 1.f / fmaxf(l, 1e-30f);

    float4 r0 = *(const float4*)(rnd + g);
    float4 r1 = *(const float4*)(rnd + g + 4);
    float rv[8] = { r0.x, r0.y, r0.z, r0.w, r1.x, r1.y, r1.z, r1.w };
    float ov[8];
#pragma unroll
    for (int e = 0; e < 8; e++) {
        float x = (nm[e] * inv + rv[e]) * 1e-5f;
        ov[e] = x > 0.f ? x : __expf(x) - 1.f;
    }
    *(float4*)(out + g)     = make_float4(ov[0], ov[1], ov[2], ov[3]);
    *(float4*)(out + g + 4) = make_float4(ov[4], ov[5], ov[6], ov[7]);
}

extern "C" void kernel_launch(void* const* d_in, const int* in_sizes, int n_in,
                              void* d_out, int out_size, void* d_ws, size_t ws_size,
                              hipStream_t stream) {
    const float* h   = (const float*)d_in[0];
    const int*   adj = (const int*)d_in[1];
    const float* W   = (const float*)d_in[2];
    const float* a   = (const float*)d_in[3];
    const float* rnd = (const float*)d_in[4];
    float* out = (float*)d_out;

    char* w = (char*)d_ws;
    short* WT    = (short*)(w);                            // 131072
    short* Bpack = (short*)(w + 131072);                   // 2097152 -> 2228224
    float* sv    = (float*)(w + 2228224);                  // 32768   -> 2260992
    float* tv    = (float*)(w + 2260992);                  // 32768   -> 2293760
    float* lpart = (float*)(w + 2293760);                  // 262144  -> 2555904
    unsigned short* num  = (unsigned short*)(w + 2555904); // 16777216 -> 19333120
    unsigned char* maskR = (unsigned char*)(w + 19333120); // 8388608  -> 27721728
    int* cnt = (int*)(w + 27721728);                       // 2048     -> 27723776 (~27.7 MB)

    prep    <<<256, 256, 0, stream>>>(W, WT, cnt);
    gemm_hW <<<512, 256, 0, stream>>>(h, WT, a, Bpack, sv, tv);
    maskattn<<<5120, 256, 0, stream>>>(adj, Bpack, sv, tv, num, lpart, maskR, cnt);
    finalize<<<512, 256, 0, stream>>>(num, lpart, rnd, out);
}

// Round 12
// 408.531 us; speedup vs baseline: 5.5742x; 5.5742x over previous
//
#include <hip/hip_runtime.h>

#define N 8192
#define IN_F 512
#define OUT_F 128
#define SPLITK 8
#define KC 1024
#define NW (N / 8)
#define LOG2E 1.4426950408889634f
#define LN2 0.6931471805599453f

typedef __attribute__((ext_vector_type(4))) float f32x4;
typedef __attribute__((ext_vector_type(8))) short bf16x8;
typedef __attribute__((ext_vector_type(8))) unsigned short u16x8;
typedef __attribute__((ext_vector_type(4))) int i32x4;

__device__ __forceinline__ short f2bf(float f) {
    union { float f; unsigned u; } c; c.f = f;
    unsigned r = c.u + 0x7FFFu + ((c.u >> 16) & 1u);
    return (short)(r >> 16);
}

__device__ __forceinline__ float exp2fast(float x) {
#if __has_builtin(__builtin_amdgcn_exp2f)
    return __builtin_amdgcn_exp2f(x);
#else
    return __expf(x * LN2);
#endif
}

__device__ __forceinline__ void load_lds16(const void* g, void* l) {
    __builtin_amdgcn_global_load_lds((const __attribute__((address_space(1))) unsigned*)g,
                                     (__attribute__((address_space(3))) unsigned*)l,
                                     16, 0, 0);
}

// ---------------------------------------------------------------- prep: W f32 -> WT bf16 [OUT_F][IN_F]
__global__ __launch_bounds__(256) void prep(const float* __restrict__ W,
                                            short* __restrict__ WT) {
    int idx = blockIdx.x * 256 + threadIdx.x;   // 65536 total
    int n = idx & (OUT_F - 1);
    int k = idx >> 7;
    WT[(size_t)n * IN_F + k] = f2bf(W[idx]);
}

// ---------------------------------------------------------------- gmask: blocks [0,512) gemm-role, [512,2560) mask-role.
// gemm: Wh=h@W -> Bpack (MFMA-fragment-packed) + fused s,t (x LOG2E).
//   Bpack[((G*8+ni)*64 + lane)*8 + e] = bf16(Wh[k][n]), G=k>>5, lane=((k>>3)&3)*16+(n&15), e=k&7, ni=n>>4.
// mask: adj int32 -> row-major bitmask (pure stream, NT loads); overlaps gemm's compute.
__global__ __launch_bounds__(256) void gmask(const float* __restrict__ h,
                                             const short* __restrict__ WT,
                                             const float* __restrict__ a,
                                             const int* __restrict__ adj,
                                             short* __restrict__ Bpack,
                                             float* __restrict__ sOut,
                                             float* __restrict__ tOut,
                                             unsigned char* __restrict__ maskR) {
    if (blockIdx.x >= 512) {
        // ------------------------------ mask role (verbatim r0 mkmask) ------------------------------
        const int wave = threadIdx.x >> 6, lane = threadIdx.x & 63;
        const size_t m = (size_t)(blockIdx.x - 512) * 4 + wave;
        const i32x4* ap = (const i32x4*)(adj + m * N);
        unsigned char* mp = maskR + m * NW;
#pragma unroll 4
        for (int it = 0; it < 16; it++) {
            int b4 = it * 128 + lane * 2;
            i32x4 a0 = __builtin_nontemporal_load(ap + b4);
            i32x4 a1 = __builtin_nontemporal_load(ap + b4 + 1);
            unsigned b = (unsigned)(a0.x > 0) | ((unsigned)(a0.y > 0) << 1) |
                         ((unsigned)(a0.z > 0) << 2) | ((unsigned)(a0.w > 0) << 3) |
                         ((unsigned)(a1.x > 0) << 4) | ((unsigned)(a1.y > 0) << 5) |
                         ((unsigned)(a1.z > 0) << 6) | ((unsigned)(a1.w > 0) << 7);
            mp[it * 64 + lane] = (unsigned char)b;
        }
        return;
    }
    // ------------------------------ gemm role (verbatim r6 gemm_hW) ------------------------------
    const int tid = threadIdx.x;
    const int wave = tid >> 6, lane = tid & 63;
    const int row16 = lane & 15, kgrp = lane >> 4;
    const int m0 = blockIdx.x * 16;
    const int kbase = wave * 128;

    f32x4 acc[8] = {};
    const float4* hp = (const float4*)(h + (size_t)(m0 + row16) * IN_F + kbase);

#pragma unroll
    for (int kk = 0; kk < 128; kk += 32) {
        float4 u0 = hp[kk / 4 + kgrp * 2];
        float4 u1 = hp[kk / 4 + kgrp * 2 + 1];
        bf16x8 af;
        af[0] = f2bf(u0.x); af[1] = f2bf(u0.y); af[2] = f2bf(u0.z); af[3] = f2bf(u0.w);
        af[4] = f2bf(u1.x); af[5] = f2bf(u1.y); af[6] = f2bf(u1.z); af[7] = f2bf(u1.w);
#pragma unroll
        for (int nt = 0; nt < 8; nt++) {
            bf16x8 bf_ = *(const bf16x8*)(WT + (size_t)(nt * 16 + row16) * IN_F + kbase + kk + kgrp * 8);
            acc[nt] = __builtin_amdgcn_mfma_f32_16x16x32_bf16(af, bf_, acc[nt], 0, 0, 0);
        }
    }

    __shared__ float red[4][16][132];
#pragma unroll
    for (int nt = 0; nt < 8; nt++)
#pragma unroll
        for (int r = 0; r < 4; r++)
            red[wave][kgrp * 4 + r][nt * 16 + row16] = acc[nt][r];
    __syncthreads();

    const int row = tid >> 4, seg = tid & 15;
    float v[8];
#pragma unroll
    for (int e = 0; e < 8; e++) {
        int c = seg * 8 + e;
        v[e] = red[0][row][c] + red[1][row][c] + red[2][row][c] + red[3][row][c];
    }
    float sp = 0.f, tp = 0.f;
#pragma unroll
    for (int e = 0; e < 8; e++) {
        sp += v[e] * a[seg * 8 + e];
        tp += v[e] * a[OUT_F + seg * 8 + e];
    }
    sp += __shfl_xor(sp, 1); tp += __shfl_xor(tp, 1);
    sp += __shfl_xor(sp, 2); tp += __shfl_xor(tp, 2);
    sp += __shfl_xor(sp, 4); tp += __shfl_xor(tp, 4);
    sp += __shfl_xor(sp, 8); tp += __shfl_xor(tp, 8);
    if (seg == 0) {
        sOut[m0 + row] = sp * LOG2E;
        tOut[m0 + row] = tp * LOG2E;
    }

    // Bpack scatter: v[e] is Wh[k=m0+row][n=seg*8+e]
    {
        const int k = m0 + row;
        const int G = k >> 5;
        const int ksub = (k >> 3) & 3;
        const int elem = k & 7;
        short* bp = Bpack + ((size_t)(G * 8 + (seg >> 1)) * 64 + ksub * 16 + (seg & 1) * 8) * 8 + elem;
#pragma unroll
        for (int e = 0; e < 8; e++)
            bp[e * 8] = f2bf(v[e]);
    }
}

// ---------------------------------------------------------------- attn: r0 structure (bitmask + LDS-staged B) with Bpack
// fragment layout -> stage is 4x contiguous 1KB global_load_lds per wave, LDS reads are stride-1 (conflict-free).
// 1-D grid 1024; kb = blockIdx.x & 7 XCD-pins the K-slice; 256 thr = 4 waves; wave = 16M x 128N x 1024K.
__global__ __launch_bounds__(256, 4) void attn(const unsigned char* __restrict__ maskR,
                                               const short* __restrict__ Bpack,
                                               const float* __restrict__ s,
                                               const float* __restrict__ t,
                                               unsigned short* __restrict__ num,
                                               float* __restrict__ lpart) {
    const int tid = threadIdx.x;
    const int wave = tid >> 6, lane = tid & 63;
    const int row16 = lane & 15, kgrp = lane >> 4;
    const int kb = blockIdx.x & 7;
    const int mb = blockIdx.x >> 3;
    const int m0 = mb * 64 + wave * 16;
    const int m  = m0 + row16;
    const int ks = kb * KC;

    __shared__ __align__(16) short Bs[2][8192];  // 32 KB: [parity][d*4096 + ni*512 + lane*8]
    __shared__ float tl[KC];                     // 4 KB

    for (int i = tid; i < KC; i += 256) tl[i] = t[ks + i];

    const float s_m = s[m];
    const int4* mp = (const int4*)(maskR + (size_t)m * NW + (ks >> 3));  // 8 int4 = 128 B
    int4 mcur = mp[0], mnxt = mp[1];

    auto stageB = [&](int sup, int par) {
        const short* src = Bpack + (size_t)(kb * 32 + sup * 2) * 4096;
#pragma unroll
        for (int it = 0; it < 4; it++)
            load_lds16(src + it * 2048 + wave * 512 + lane * 8,
                       &Bs[par][it * 2048 + wave * 512]);
    };

    f32x4 acc[8] = {};
    float lsum = 0.f;

    stageB(0, 0);
    __syncthreads();   // tl + B super 0 ready

    for (int sp2 = 0; sp2 < 8; sp2++) {          // mcur = mask int4 #sp2 (2 supersteps)
#pragma unroll
        for (int ss = 0; ss < 2; ss++) {
            const int sp = sp2 * 2 + ss;         // super 0..15
            const int par = ss;                  // == sp & 1
            if (sp + 1 < 16) stageB(sp + 1, par ^ 1);   // async into other parity
#pragma unroll
            for (int d = 0; d < 2; d++) {
                const int g = sp * 2 + d;        // slice 0..31
                const unsigned dw = (unsigned)((const int*)&mcur)[ss * 2 + d];
                const unsigned mbyte = (dw >> (kgrp * 8)) & 0xFFu;

                const float* tp = tl + g * 32 + kgrp * 8;
                float4 tA = *(const float4*)tp;
                float4 tB = *(const float4*)(tp + 4);
                float tv[8] = { tA.x, tA.y, tA.z, tA.w, tB.x, tB.y, tB.z, tB.w };

                bf16x8 bfr[8];
#pragma unroll
                for (int ni = 0; ni < 8; ni++)
                    bfr[ni] = *(const bf16x8*)(&Bs[par][d * 4096 + ni * 512 + lane * 8]);

                unsigned pu[8];
#pragma unroll
                for (int e = 0; e < 8; e++) {
                    float x = s_m + tv[e];
                    x = fmaxf(x, 0.2f * x);                    // leaky relu
                    float p = exp2fast(x);                     // s,t pre-scaled by log2e
                    unsigned u = __float_as_uint(p) & 0xFFFF0000u;
                    u = ((mbyte >> e) & 1u) ? u : 0u;
                    lsum += __uint_as_float(u);                // consistent with numerator
                    pu[e] = u;
                }
                bf16x8 af;
                unsigned* au = (unsigned*)&af;
#pragma unroll
                for (int q = 0; q < 4; q++) au[q] = (pu[2 * q] >> 16) | pu[2 * q + 1];
#pragma unroll
                for (int ni = 0; ni < 8; ni++)
                    acc[ni] = __builtin_amdgcn_mfma_f32_16x16x32_bf16(af, bfr[ni], acc[ni], 0, 0, 0);
            }
            __syncthreads();   // drains stage of sp+1; guards parity reuse
        }
        mcur = mnxt;
        if (sp2 + 2 < 8) mnxt = mp[sp2 + 2];
    }

    // row sum across kgrp lanes
    {
        float v = lsum;
        v += __shfl_xor(v, 16);
        v += __shfl_xor(v, 32);
        if (kgrp == 0) lpart[(size_t)kb * N + m] = v;
    }

    // partial numerator, bf16: C layout row = kgrp*4+r (m within 16), col = ni*16+row16
    unsigned short* np_ = num + ((size_t)kb * N + m0) * OUT_F;
#pragma unroll
    for (int ni = 0; ni < 8; ni++) {
        int n = ni * 16 + row16;
#pragma unroll
        for (int r = 0; r < 4; r++)
            np_[(size_t)(kgrp * 4 + r) * OUT_F + n] = (unsigned short)f2bf(acc[ni][r]);
    }
}

// ---------------------------------------------------------------- finalize: reduce bf16 splits, /l, +rnd, elu
__global__ __launch_bounds__(256) void finalize(const unsigned short* __restrict__ num,
                                                const float* __restrict__ lpart,
                                                const float* __restrict__ rnd,
                                                float* __restrict__ out) {
    int idx = blockIdx.x * 256 + threadIdx.x;   // one thread = 8 outputs
    int m = idx >> 4;
    int c = (idx & 15) * 8;
    size_t g = (size_t)m * OUT_F + c;

    float nm[8] = {};
#pragma unroll
    for (int bk = 0; bk < SPLITK; bk++) {
        u16x8 v = *(const u16x8*)(num + (size_t)bk * N * OUT_F + g);
#pragma unroll
        for (int e = 0; e < 8; e++) nm[e] += __uint_as_float((unsigned)v[e] << 16);
    }
    float l = 0.f;
#pragma unroll
    for (int bk = 0; bk < SPLITK; bk++) l += lpart[(size_t)bk * N + m];
    float inv = 1.f / fmaxf(l, 1e-30f);

    float4 r0 = *(const float4*)(rnd + g);
    float4 r1 = *(const float4*)(rnd + g + 4);
    float rv[8] = { r0.x, r0.y, r0.z, r0.w, r1.x, r1.y, r1.z, r1.w };
    float ov[8];
#pragma unroll
    for (int e = 0; e < 8; e++) {
        float x = (nm[e] * inv + rv[e]) * 1e-5f;
        ov[e] = x > 0.f ? x : __expf(x) - 1.f;
    }
    *(float4*)(out + g)     = make_float4(ov[0], ov[1], ov[2], ov[3]);
    *(float4*)(out + g + 4) = make_float4(ov[4], ov[5], ov[6], ov[7]);
}

extern "C" void kernel_launch(void* const* d_in, const int* in_sizes, int n_in,
                              void* d_out, int out_size, void* d_ws, size_t ws_size,
                              hipStream_t stream) {
    const float* h   = (const float*)d_in[0];
    const int*   adj = (const int*)d_in[1];
    const float* W   = (const float*)d_in[2];
    const float* a   = (const float*)d_in[3];
    const float* rnd = (const float*)d_in[4];
    float* out = (float*)d_out;

    char* w = (char*)d_ws;
    short* WT    = (short*)(w);                            // 131072
    short* Bpack = (short*)(w + 131072);                   // 2097152 -> 2228224
    float* sv    = (float*)(w + 2228224);                  // 32768   -> 2260992
    float* tv    = (float*)(w + 2260992);                  // 32768   -> 2293760
    float* lpart = (float*)(w + 2293760);                  // 262144  -> 2555904
    unsigned short* num  = (unsigned short*)(w + 2555904); // 16777216 -> 19333120
    unsigned char* maskR = (unsigned char*)(w + 19333120); // 8388608  -> 27721728 (~27 MB)

    prep    <<<256, 256, 0, stream>>>(W, WT);
    gmask   <<<2560, 256, 0, stream>>>(h, WT, a, adj, Bpack, sv, tv, maskR);
    attn    <<<1024, 256, 0, stream>>>(maskR, Bpack, sv, tv, num, lpart);
    finalize<<<512, 256, 0, stream>>>(num, lpart, rnd, out);
}